// Round 2
// baseline (381.627 us; speedup 1.0000x reference)
//
#include <hip/hip_runtime.h>
#include <math.h>

// Problem shape (fixed by the reference):
//   q: [NB, DK] fp32, k: [NB, L, DK] fp32, v: [NB, L, DV] fp32
//   out0: [NB, DV] fp32, out1 (attn): [NB, L] fp32  (concatenated in d_out)
#define NB 1024
#define L  2048
#define DK 128
#define DV 128

static constexpr float INV_TEMP = 0.088388347648318447f; // 1/sqrt(128)

// Single-pass flash-style kernel. One block per batch row, 512 threads = 8 waves.
// Each wave owns a contiguous slice of 256 l-rows and streams k[l] and v[l]
// together, maintaining an online (max, sum, acc) triple with branchless
// rescaling. Raw scores go to LDS so attn = exp(s - gmax)/gsum can be emitted
// exactly in the epilogue. Only 2 __syncthreads total (epilogue combine).
__global__ __launch_bounds__(512, 8)
void mvsdpa_kernel(const float* __restrict__ q,
                   const float* __restrict__ k,
                   const float* __restrict__ v,
                   float* __restrict__ out,    // [NB, DV]
                   float* __restrict__ attn)   // [NB, L]
{
    const int b    = blockIdx.x;
    const int tid  = threadIdx.x;       // 0..511
    const int wave = tid >> 6;          // 0..7
    const int lane = tid & 63;
    const int half = lane >> 5;         // 0/1: which row of the pair
    const int l32  = lane & 31;         // lane within 32-group (covers DK via float4)

    __shared__ float s_scores[L];        // 8 KB: raw (scaled) scores
    __shared__ float s_m[8];             // per-wave running max
    __shared__ float s_s[8];             // per-wave running sum
    __shared__ float s_partial[8][DV];   // 4 KB: per-wave PV partials

    const float* qb = q + (size_t)b * DK;
    const float* kb = k + (size_t)b * (size_t)L * DK;
    const float* vb = v + (size_t)b * (size_t)L * DV;

    const float4 q4 = *reinterpret_cast<const float4*>(qb + l32 * 4);

    // Wave w owns rows [w*256, (w+1)*256): contiguous k/v streaming per wave.
    const int l0 = wave * (L / 8);

    float  m   = -INFINITY;
    float  sum = 0.f;
    float2 acc = make_float2(0.f, 0.f);

    for (int i = 0; i < L / 8; i += 2) {
        const int l = l0 + i;   // lanes 0-31: row l; lanes 32-63: row l+1
        const float4 k4 = *reinterpret_cast<const float4*>(kb + (size_t)(l + half) * DK + l32 * 4);
        const float2 v0 = *reinterpret_cast<const float2*>(vb + (size_t)l       * DV + lane * 2);
        const float2 v1 = *reinterpret_cast<const float2*>(vb + (size_t)(l + 1) * DV + lane * 2);

        // dot(q, k_row) over the 32-lane half-group
        float d = q4.x * k4.x + q4.y * k4.y + q4.z * k4.z + q4.w * k4.w;
        d += __shfl_xor(d, 1);
        d += __shfl_xor(d, 2);
        d += __shfl_xor(d, 4);
        d += __shfl_xor(d, 8);
        d += __shfl_xor(d, 16);
        d *= INV_TEMP;
        if (l32 == 0) s_scores[l + half] = d;   // lanes 0 and 32 write rows l, l+1

        const float s0 = __shfl(d, 0);
        const float s1 = __shfl(d, 32);

        // branchless online-softmax update (scale == 1.0 when max unchanged;
        // first iter: m = -inf -> scale = 0, acc/sum start clean)
        const float mn    = fmaxf(m, fmaxf(s0, s1));
        const float scale = __expf(m - mn);
        const float p0    = __expf(s0 - mn);
        const float p1    = __expf(s1 - mn);
        m   = mn;
        sum = sum * scale + p0 + p1;
        acc.x = acc.x * scale + p0 * v0.x + p1 * v1.x;
        acc.y = acc.y * scale + p0 * v0.y + p1 * v1.y;
    }

    if (lane == 0) { s_m[wave] = m; s_s[wave] = sum; }
    __syncthreads();

    // global max / sum (redundant per-thread, 8 elements — cheap)
    float gmax = s_m[0];
    #pragma unroll
    for (int w = 1; w < 8; ++w) gmax = fmaxf(gmax, s_m[w]);
    float gsum = 0.f;
    #pragma unroll
    for (int w = 0; w < 8; ++w) gsum += s_s[w] * __expf(s_m[w] - gmax);
    const float inv = 1.0f / gsum;

    // attn output (coalesced, 4 elements/thread)
    float* attn_b = attn + (size_t)b * L;
    #pragma unroll
    for (int i = 0; i < 4; ++i) {
        const int idx = tid + i * 512;
        attn_b[idx] = __expf(s_scores[idx] - gmax) * inv;
    }

    // combine per-wave PV partials
    const float wscale = __expf(m - gmax);
    reinterpret_cast<float2*>(s_partial[wave])[lane] =
        make_float2(acc.x * wscale, acc.y * wscale);
    __syncthreads();
    if (tid < DV) {
        float s = 0.f;
        #pragma unroll
        for (int w = 0; w < 8; ++w) s += s_partial[w][tid];
        out[(size_t)b * DV + tid] = s * inv;
    }
}

extern "C" void kernel_launch(void* const* d_in, const int* in_sizes, int n_in,
                              void* d_out, int out_size, void* d_ws, size_t ws_size,
                              hipStream_t stream) {
    const float* q = (const float*)d_in[0];
    const float* k = (const float*)d_in[1];
    const float* v = (const float*)d_in[2];
    float* out  = (float*)d_out;                   // [NB, DV]
    float* attn = (float*)d_out + (size_t)NB * DV; // [NB, L]
    mvsdpa_kernel<<<NB, 512, 0, stream>>>(q, k, v, out, attn);
}

// Round 3
// 355.320 us; speedup vs baseline: 1.0740x; 1.0740x over previous
//
#include <hip/hip_runtime.h>
#include <math.h>

// Problem shape (fixed by the reference):
//   q: [NB, DK] fp32, k: [NB, L, DK] fp32, v: [NB, L, DV] fp32
//   out0: [NB, DV] fp32, out1 (attn): [NB, L] fp32  (concatenated in d_out)
#define NB 1024
#define L  2048
#define DK 128
#define DV 128

static constexpr float INV_TEMP = 0.088388347648318447f; // 1/sqrt(128)

// 3-phase kernel (round-1 skeleton, tuned):
//  P1: QK^T — 4 rows/wave/iter, two independent float4-load + shfl-reduce chains
//  P2: block softmax (float4 LDS + float4 attn stores); v-prefetch issued
//      BEFORE the barrier keeps VMEM busy through the softmax window
//  P3: PV — float4 v loads (16B/lane), half-wave row split, LDS combine
__global__ __launch_bounds__(512, 8)
void mvsdpa_kernel(const float* __restrict__ q,
                   const float* __restrict__ k,
                   const float* __restrict__ v,
                   float* __restrict__ out,    // [NB, DV]
                   float* __restrict__ attn)   // [NB, L]
{
    const int b    = blockIdx.x;
    const int tid  = threadIdx.x;       // 0..511
    const int wave = tid >> 6;          // 0..7
    const int lane = tid & 63;
    const int half = lane >> 5;         // 0/1
    const int l32  = lane & 31;

    __shared__ float s_scores[L];          // 8 KB: scores, then probabilities
    __shared__ float s_red[16];
    __shared__ float s_partial[16][DV];    // 8 KB: per-(wave,half) PV partials

    const float* qb = q + (size_t)b * DK;
    const float* kb = k + (size_t)b * (size_t)L * DK;
    const float* vb = v + (size_t)b * (size_t)L * DV;

    const float4 q4 = *reinterpret_cast<const float4*>(qb + l32 * 4);

    // each (wave, half) pair owns rows 32*i + rbase and 32*i + rbase + 16
    const int rbase = wave * 2 + half;

    // ---- Phase 1: QK^T ----
    for (int i = 0; i < L / 32; ++i) {
        const int r0 = i * 32 + rbase;
        const int r1 = r0 + 16;
        const float4 k40 = *reinterpret_cast<const float4*>(kb + (size_t)r0 * DK + l32 * 4);
        const float4 k41 = *reinterpret_cast<const float4*>(kb + (size_t)r1 * DK + l32 * 4);
        float d0 = q4.x * k40.x + q4.y * k40.y + q4.z * k40.z + q4.w * k40.w;
        float d1 = q4.x * k41.x + q4.y * k41.y + q4.z * k41.z + q4.w * k41.w;
        #pragma unroll
        for (int m = 1; m < 32; m <<= 1) {   // two independent reduce chains (ILP)
            d0 += __shfl_xor(d0, m);
            d1 += __shfl_xor(d1, m);
        }
        if (l32 == 0) {
            s_scores[r0] = d0 * INV_TEMP;
            s_scores[r1] = d1 * INV_TEMP;
        }
    }

    // ---- cross-barrier v prefetch (keeps VMEM busy during softmax) ----
    const float4 vp0 = *reinterpret_cast<const float4*>(vb + (size_t)rbase        * DV + l32 * 4);
    const float4 vp1 = *reinterpret_cast<const float4*>(vb + (size_t)(rbase + 16) * DV + l32 * 4);

    __syncthreads();

    // ---- Phase 2: softmax over L ----
    float4 sv = *reinterpret_cast<const float4*>(&s_scores[tid * 4]);
    float lmax = fmaxf(fmaxf(sv.x, sv.y), fmaxf(sv.z, sv.w));
    #pragma unroll
    for (int m = 1; m < 64; m <<= 1) lmax = fmaxf(lmax, __shfl_xor(lmax, m));
    if (lane == 0) s_red[wave] = lmax;
    __syncthreads();
    float gmax = s_red[0];
    #pragma unroll
    for (int w = 1; w < 8; ++w) gmax = fmaxf(gmax, s_red[w]);

    sv.x = __expf(sv.x - gmax);
    sv.y = __expf(sv.y - gmax);
    sv.z = __expf(sv.z - gmax);
    sv.w = __expf(sv.w - gmax);
    float lsum = sv.x + sv.y + sv.z + sv.w;
    #pragma unroll
    for (int m = 1; m < 64; m <<= 1) lsum += __shfl_xor(lsum, m);
    if (lane == 0) s_red[8 + wave] = lsum;
    __syncthreads();
    float gsum = 0.f;
    #pragma unroll
    for (int w = 0; w < 8; ++w) gsum += s_red[8 + w];
    const float inv = 1.0f / gsum;

    sv.x *= inv; sv.y *= inv; sv.z *= inv; sv.w *= inv;
    *reinterpret_cast<float4*>(&s_scores[tid * 4]) = sv;                      // p -> LDS
    *reinterpret_cast<float4*>(attn + (size_t)b * L + tid * 4) = sv;          // coalesced
    __syncthreads();

    // ---- Phase 3: PV ----
    float4 acc = make_float4(0.f, 0.f, 0.f, 0.f);
    {   // i = 0 uses the prefetched rows
        const float p0 = s_scores[rbase];
        const float p1 = s_scores[rbase + 16];
        acc.x = p0 * vp0.x + p1 * vp1.x;
        acc.y = p0 * vp0.y + p1 * vp1.y;
        acc.z = p0 * vp0.z + p1 * vp1.z;
        acc.w = p0 * vp0.w + p1 * vp1.w;
    }
    for (int i = 1; i < L / 32; ++i) {
        const int r0 = i * 32 + rbase;
        const int r1 = r0 + 16;
        const float4 v0 = *reinterpret_cast<const float4*>(vb + (size_t)r0 * DV + l32 * 4);
        const float4 v1 = *reinterpret_cast<const float4*>(vb + (size_t)r1 * DV + l32 * 4);
        const float p0 = s_scores[r0];    // broadcast within half-wave
        const float p1 = s_scores[r1];
        acc.x += p0 * v0.x + p1 * v1.x;
        acc.y += p0 * v0.y + p1 * v1.y;
        acc.z += p0 * v0.z + p1 * v1.z;
        acc.w += p0 * v0.w + p1 * v1.w;
    }
    *reinterpret_cast<float4*>(&s_partial[wave * 2 + half][l32 * 4]) = acc;
    __syncthreads();
    if (tid < DV) {
        float s = 0.f;
        #pragma unroll
        for (int w = 0; w < 16; ++w) s += s_partial[w][tid];
        out[(size_t)b * DV + tid] = s;
    }
}

extern "C" void kernel_launch(void* const* d_in, const int* in_sizes, int n_in,
                              void* d_out, int out_size, void* d_ws, size_t ws_size,
                              hipStream_t stream) {
    const float* q = (const float*)d_in[0];
    const float* k = (const float*)d_in[1];
    const float* v = (const float*)d_in[2];
    float* out  = (float*)d_out;                   // [NB, DV]
    float* attn = (float*)d_out + (size_t)NB * DV; // [NB, L]
    mvsdpa_kernel<<<NB, 512, 0, stream>>>(q, k, v, out, attn);
}

// Round 5
// 318.091 us; speedup vs baseline: 1.1997x; 1.1170x over previous
//
#include <hip/hip_runtime.h>
#include <math.h>

// Problem shape (fixed by the reference):
//   q: [NB, DK] fp32, k: [NB, L, DK] fp32, v: [NB, L, DV] fp32
//   out0: [NB, DV] fp32, out1 (attn): [NB, L] fp32  (concatenated in d_out)
#define NB 1024
#define L  2048
#define DK 128
#define DV 128

static constexpr float INV_TEMP = 0.088388347648318447f; // 1/sqrt(128)

// clang native vector type: __builtin_nontemporal_load requires a pointer to
// scalar or native-vector (HIP_vector_type float4 is a struct -> rejected).
typedef float f32x4 __attribute__((ext_vector_type(4)));

__device__ __forceinline__ f32x4 nt_load4(const float* p) {
    return __builtin_nontemporal_load(reinterpret_cast<const f32x4*>(p));
}

// 3-phase kernel, round-3 skeleton plus:
//  - nontemporal k/v loads (streaming data, zero reuse -> skip L2 fill)
//  - 4-deep float4 v-prefetch issued before the P1->P2 barrier
//  - softmax does max+sum in ONE pass per wave (one fewer block barrier):
//      gsum = sum_w lsum_w * exp(lmax_w - gmax)
__global__ __launch_bounds__(512, 8)
void mvsdpa_kernel(const float* __restrict__ q,
                   const float* __restrict__ k,
                   const float* __restrict__ v,
                   float* __restrict__ out,    // [NB, DV]
                   float* __restrict__ attn)   // [NB, L]
{
    const int b    = blockIdx.x;
    const int tid  = threadIdx.x;       // 0..511
    const int wave = tid >> 6;          // 0..7
    const int lane = tid & 63;
    const int half = lane >> 5;         // 0/1
    const int l32  = lane & 31;

    __shared__ float s_scores[L];          // 8 KB: scores, then probabilities
    __shared__ float s_red[16];            // [0..7]=wave max, [8..15]=wave expsum
    __shared__ float s_partial[16][DV];    // 8 KB: per-(wave,half) PV partials

    const float* qb = q + (size_t)b * DK;
    const float* kb = k + (size_t)b * (size_t)L * DK;
    const float* vb = v + (size_t)b * (size_t)L * DV;

    const f32x4 q4 = *reinterpret_cast<const f32x4*>(qb + l32 * 4);

    // each (wave, half) pair owns rows 32*i + rbase and 32*i + rbase + 16
    const int rbase = wave * 2 + half;

    // ---- Phase 1: QK^T ----
    for (int i = 0; i < L / 32; ++i) {
        const int r0 = i * 32 + rbase;
        const int r1 = r0 + 16;
        const f32x4 k40 = nt_load4(kb + (size_t)r0 * DK + l32 * 4);
        const f32x4 k41 = nt_load4(kb + (size_t)r1 * DK + l32 * 4);
        float d0 = q4.x * k40.x + q4.y * k40.y + q4.z * k40.z + q4.w * k40.w;
        float d1 = q4.x * k41.x + q4.y * k41.y + q4.z * k41.z + q4.w * k41.w;
        #pragma unroll
        for (int m = 1; m < 32; m <<= 1) {   // two independent reduce chains (ILP)
            d0 += __shfl_xor(d0, m);
            d1 += __shfl_xor(d1, m);
        }
        if (l32 == 0) {
            s_scores[r0] = d0 * INV_TEMP;
            s_scores[r1] = d1 * INV_TEMP;
        }
    }

    // ---- cross-barrier v prefetch: 4 rows/lane stay in flight through softmax ----
    const f32x4 vp0 = nt_load4(vb + (size_t)(rbase)      * DV + l32 * 4);
    const f32x4 vp1 = nt_load4(vb + (size_t)(rbase + 16) * DV + l32 * 4);
    const f32x4 vp2 = nt_load4(vb + (size_t)(rbase + 32) * DV + l32 * 4);
    const f32x4 vp3 = nt_load4(vb + (size_t)(rbase + 48) * DV + l32 * 4);

    __syncthreads();

    // ---- Phase 2: softmax over L (single pass per wave: max then expsum) ----
    f32x4 sv = *reinterpret_cast<const f32x4*>(&s_scores[tid * 4]);
    float lmax = fmaxf(fmaxf(sv.x, sv.y), fmaxf(sv.z, sv.w));
    #pragma unroll
    for (int m = 1; m < 64; m <<= 1) lmax = fmaxf(lmax, __shfl_xor(lmax, m));

    f32x4 ev;
    ev.x = __expf(sv.x - lmax);
    ev.y = __expf(sv.y - lmax);
    ev.z = __expf(sv.z - lmax);
    ev.w = __expf(sv.w - lmax);
    float lsum = ev.x + ev.y + ev.z + ev.w;
    #pragma unroll
    for (int m = 1; m < 64; m <<= 1) lsum += __shfl_xor(lsum, m);

    if (lane == 0) { s_red[wave] = lmax; s_red[8 + wave] = lsum; }
    __syncthreads();

    float gmax = s_red[0];
    #pragma unroll
    for (int w = 1; w < 8; ++w) gmax = fmaxf(gmax, s_red[w]);
    float gsum = 0.f;
    #pragma unroll
    for (int w = 0; w < 8; ++w) gsum += s_red[8 + w] * __expf(s_red[w] - gmax);
    const float scale = __expf(lmax - gmax) / gsum;   // folds wave->global rescale

    sv.x = ev.x * scale; sv.y = ev.y * scale; sv.z = ev.z * scale; sv.w = ev.w * scale;
    *reinterpret_cast<f32x4*>(&s_scores[tid * 4]) = sv;                 // p -> LDS
    *reinterpret_cast<f32x4*>(attn + (size_t)b * L + tid * 4) = sv;     // coalesced
    __syncthreads();

    // ---- Phase 3: PV ----
    f32x4 acc;
    {   // i = 0,1 use the prefetched rows
        const float p0 = s_scores[rbase];
        const float p1 = s_scores[rbase + 16];
        const float p2 = s_scores[rbase + 32];
        const float p3 = s_scores[rbase + 48];
        acc.x = p0 * vp0.x + p1 * vp1.x + p2 * vp2.x + p3 * vp3.x;
        acc.y = p0 * vp0.y + p1 * vp1.y + p2 * vp2.y + p3 * vp3.y;
        acc.z = p0 * vp0.z + p1 * vp1.z + p2 * vp2.z + p3 * vp3.z;
        acc.w = p0 * vp0.w + p1 * vp1.w + p2 * vp2.w + p3 * vp3.w;
    }
    for (int i = 2; i < L / 32; ++i) {
        const int r0 = i * 32 + rbase;
        const int r1 = r0 + 16;
        const f32x4 v0 = nt_load4(vb + (size_t)r0 * DV + l32 * 4);
        const f32x4 v1 = nt_load4(vb + (size_t)r1 * DV + l32 * 4);
        const float p0 = s_scores[r0];    // broadcast within half-wave
        const float p1 = s_scores[r1];
        acc.x += p0 * v0.x + p1 * v1.x;
        acc.y += p0 * v0.y + p1 * v1.y;
        acc.z += p0 * v0.z + p1 * v1.z;
        acc.w += p0 * v0.w + p1 * v1.w;
    }
    *reinterpret_cast<f32x4*>(&s_partial[wave * 2 + half][l32 * 4]) = acc;
    __syncthreads();
    if (tid < DV) {
        float s = 0.f;
        #pragma unroll
        for (int w = 0; w < 16; ++w) s += s_partial[w][tid];
        out[(size_t)b * DV + tid] = s;
    }
}

extern "C" void kernel_launch(void* const* d_in, const int* in_sizes, int n_in,
                              void* d_out, int out_size, void* d_ws, size_t ws_size,
                              hipStream_t stream) {
    const float* q = (const float*)d_in[0];
    const float* k = (const float*)d_in[1];
    const float* v = (const float*)d_in[2];
    float* out  = (float*)d_out;                   // [NB, DV]
    float* attn = (float*)d_out + (size_t)NB * DV; // [NB, L]
    mvsdpa_kernel<<<NB, 512, 0, stream>>>(q, k, v, out, attn);
}